// Round 4
// baseline (485.025 us; speedup 1.0000x reference)
//
#include <hip/hip_runtime.h>

typedef _Float16 f16x8 __attribute__((ext_vector_type(8)));
typedef float f32x4 __attribute__((ext_vector_type(4)));

#define EXP_CLIP 10.0f
#define FEPS 1e-6f
#define WSCALE 16384.0f      // 2^14 weight prescale (kills fp16-denorm weights)
#define WDESCALE (1.0f/16384.0f)
#define PSCALE 1024.0f       // proj weight prescale
#define PDESCALE (1.0f/1024.0f)

__device__ __forceinline__ _Float16 cvh(float v) {
  v = fminf(fmaxf(v, -60000.f), 60000.f);
  return (_Float16)v;
}

__device__ __forceinline__ void gload_lds16(const void* g, void* l) {
  __builtin_amdgcn_global_load_lds(
      (const __attribute__((address_space(1))) void*)g,
      (__attribute__((address_space(3))) void*)l, 16, 0, 0);
}

// XOR-swizzled LDS offset (half units) for a [*][64]-half tile.
__device__ __forceinline__ int swz(int row, int colh) {
  return row * 64 + (colh ^ ((row & 7) << 3));
}

// ---------------------------------------------------------------------------
// Prep: per (layer, j) block, 512 threads over i.
// ---------------------------------------------------------------------------
template <bool EMIT_LO>
__global__ __launch_bounds__(512)
void prep_weights(const float* __restrict__ alphas, const float* __restrict__ scale,
                  const float* __restrict__ bias, _Float16* __restrict__ Wh,
                  _Float16* __restrict__ Wl, float* __restrict__ biasvec) {
  int j = blockIdx.x;
  int i = threadIdx.x;
  size_t base = ((size_t)i * 512 + j) * 8;
  float a[8];
#pragma unroll
  for (int k = 0; k < 8; ++k) a[k] = alphas[base + k];
  float m = a[0];
#pragma unroll
  for (int k = 1; k < 8; ++k) m = fmaxf(m, a[k]);
  float e[8], sum = 0.f;
#pragma unroll
  for (int k = 0; k < 8; ++k) { e[k] = __expf(a[k] - m); sum += e[k]; }
  float inv = 1.f / sum;
  float bp = 0.f;
#pragma unroll
  for (int k = 1; k < 8; ++k) {
    float w = e[k] * inv;
    float ws = fminf(fmaxf(w * scale[base + k] * WSCALE, -60000.f), 60000.f);
    _Float16 wh = (_Float16)ws;
    size_t o = (size_t)j * 3584 + (size_t)(k - 1) * 512 + i;
    Wh[o] = wh;
    if (EMIT_LO) Wl[o] = (_Float16)(ws - (float)wh);
    bp += w * bias[base + k];
  }
  __shared__ float red[512];
  red[i] = bp;
  __syncthreads();
  for (int off = 256; off > 0; off >>= 1) {
    if (i < off) red[i] += red[i + off];
    __syncthreads();
  }
  if (i == 0) biasvec[j] = red[0];
}

// ---------------------------------------------------------------------------
// Featurize (layer-2 input): h [rows][512] fp32 -> out [rows][3584] fp16
// ---------------------------------------------------------------------------
__global__ __launch_bounds__(256)
void featurize_k(const float* __restrict__ in, _Float16* __restrict__ out, int total) {
  int idx = blockIdx.x * 256 + threadIdx.x;
  if (idx >= total) return;
  int b = idx >> 9, i = idx & 511;
  float x = in[idx];
  float x2 = x * x, x3 = x2 * x;
  float ex = __expf(fminf(fmaxf(x, -EXP_CLIP), EXP_CLIP));
  float ln = __logf(fabsf(x) + FEPS);
  float rc = x / (x2 + FEPS);
  float sn = __sinf(x);
  _Float16* o = out + (size_t)b * 3584 + i;
  o[0]    = cvh(x);
  o[512]  = cvh(x2);
  o[1024] = cvh(x3);
  o[1536] = cvh(ex);
  o[2048] = cvh(ln);
  o[2560] = cvh(rc);
  o[3072] = cvh(sn);
}

__global__ __launch_bounds__(256)
void cvt_half_k(const float* __restrict__ in, _Float16* __restrict__ out, int n) {
  int idx = blockIdx.x * 256 + threadIdx.x;
  if (idx < n) out[idx] = (_Float16)(in[idx] * PSCALE);
}

// ---------------------------------------------------------------------------
// Layer-1 fused GEMM, pipelined: 256x128 tile, 8 waves (4x2), BK=64, 1 blk/CU.
// B (weights hi/lo) double-buffered via global_load_lds + counted vmcnt(4).
// A: featurize(t+1)->regs interleaved with MFMA(t); ds_write after barrier.
// ---------------------------------------------------------------------------
__global__ __launch_bounds__(512, 2)
void gemm_l1(const float* __restrict__ X, const _Float16* __restrict__ Wh,
             const _Float16* __restrict__ Wl, const float* __restrict__ bias,
             float* __restrict__ H) {
  __shared__ __align__(16) _Float16 AhS[256 * 64];      // 32 KB
  __shared__ __align__(16) _Float16 AlS[256 * 64];      // 32 KB
  __shared__ __align__(16) _Float16 BhS[2][128 * 64];   // 32 KB
  __shared__ __align__(16) _Float16 BlS[2][128 * 64];   // 32 KB
  const int K = 3584, NT = 56;
  int lin = blockIdx.x;                 // 256 blocks
  int wg = (lin & 7) * 32 + (lin >> 3); // XCD-contiguous remap (q=32)
  int bn = wg & 3, bm = wg >> 2;
  int row0 = bm * 256, col0 = bn * 128;
  int tid = threadIdx.x, lane = tid & 63, wave = tid >> 6;
  int wm = wave >> 1, wn = wave & 1;    // 4x2 wave grid, wave tile 64x64
  int l16 = lane & 15, lh = lane >> 4;
  int sr = lane >> 3, sc = ((lane & 7) * 8) ^ (sr << 3);  // pre-swizzled src col
  int fr = tid >> 3, fc = (tid & 7) * 8;                  // featurize row/col

  const _Float16* BghBase = Wh + (size_t)col0 * K;
  const _Float16* BglBase = Wl + (size_t)col0 * K;

  f32x4 acc[4][4];
#pragma unroll
  for (int m = 0; m < 4; ++m)
#pragma unroll
    for (int n = 0; n < 4; ++n) acc[m][n] = (f32x4){0.f, 0.f, 0.f, 0.f};

  f16x8 hv[4], lv[4];

  auto stageB = [&](int t, int p) {  // 4 vmem issues per wave
    int kk = t * 64;
#pragma unroll
    for (int it = 0; it < 2; ++it) {
      int chunk = wave * 2 + it;      // 0..15, wave-uniform
      int r = chunk * 8 + sr;
      gload_lds16(BghBase + (size_t)r * K + kk + sc, &BhS[p][chunk * 512]);
      gload_lds16(BglBase + (size_t)r * K + kk + sc, &BlS[p][chunk * 512]);
    }
  };

  auto featurize = [&](int t) {       // -> hv/lv regs (no LDS)
    int kp = (t * 64) >> 9, i0 = (t * 64) & 511;
#pragma unroll
    for (int it = 0; it < 4; ++it) {
      const float* xp = X + (size_t)(row0 + it * 64 + fr) * 512 + i0 + fc;
      float4 x01 = *(const float4*)xp;
      float4 x23 = *(const float4*)(xp + 4);
      float xv[8] = {x01.x, x01.y, x01.z, x01.w, x23.x, x23.y, x23.z, x23.w};
#pragma unroll
      for (int e = 0; e < 8; ++e) {
        float x = xv[e], f;
        switch (kp) {
          case 0: f = x; break;
          case 1: f = x * x; break;
          case 2: f = x * x * x; break;
          case 3: f = __expf(fminf(fmaxf(x, -EXP_CLIP), EXP_CLIP)); break;
          case 4: f = __logf(fabsf(x) + FEPS); break;
          case 5: f = x / (x * x + FEPS); break;
          default: f = __sinf(x); break;
        }
        _Float16 fh = (_Float16)f;
        hv[it][e] = fh;
        lv[it][e] = (_Float16)(f - (float)fh);
      }
    }
  };

  auto writeA = [&]() {
#pragma unroll
    for (int it = 0; it < 4; ++it) {
      int wo = swz(it * 64 + fr, fc);
      *(f16x8*)&AhS[wo] = hv[it];
      *(f16x8*)&AlS[wo] = lv[it];
    }
  };

  // ---- prologue ----
  stageB(0, 0);
  featurize(0);
  writeA();
  stageB(1, 1);
  asm volatile("s_waitcnt vmcnt(4) lgkmcnt(0)" ::: "memory");
  __builtin_amdgcn_sched_barrier(0);
  __builtin_amdgcn_s_barrier();

#pragma unroll 1
  for (int t = 0; t < NT; ++t) {
    int p = t & 1;
    if (t + 1 < NT) featurize(t + 1);   // VALU+VMEM, overlaps MFMA below
    // ---- MFMA phase on A(t), B[p] ----
#pragma unroll
    for (int kc = 0; kc < 2; ++kc) {
      f16x8 ah[4], al[4];
#pragma unroll
      for (int m = 0; m < 4; ++m) {
        int off = swz(wm * 64 + m * 16 + l16, kc * 32 + lh * 8);
        ah[m] = *(const f16x8*)&AhS[off];
        al[m] = *(const f16x8*)&AlS[off];
      }
#pragma unroll
      for (int n = 0; n < 4; ++n) {
        int ob = swz(wn * 64 + n * 16 + l16, kc * 32 + lh * 8);
        f16x8 bh = *(const f16x8*)&BhS[p][ob];
        f16x8 bl = *(const f16x8*)&BlS[p][ob];
#pragma unroll
        for (int m = 0; m < 4; ++m) {
          acc[m][n] = __builtin_amdgcn_mfma_f32_16x16x32_f16(ah[m], bh, acc[m][n], 0, 0, 0);
          acc[m][n] = __builtin_amdgcn_mfma_f32_16x16x32_f16(al[m], bh, acc[m][n], 0, 0, 0);
          acc[m][n] = __builtin_amdgcn_mfma_f32_16x16x32_f16(ah[m], bl, acc[m][n], 0, 0, 0);
        }
      }
    }
    __builtin_amdgcn_sched_barrier(0);
    __builtin_amdgcn_s_barrier();       // compute on A(t)/B[p] done
    if (t + 1 < NT) {
      writeA();                          // A(t+1) -> LDS
      if (t + 2 < NT) {
        stageB(t + 2, p);                // prefetch into freed buffer
        asm volatile("s_waitcnt vmcnt(4) lgkmcnt(0)" ::: "memory");
      } else {
        asm volatile("s_waitcnt vmcnt(0) lgkmcnt(0)" ::: "memory");
      }
      __builtin_amdgcn_sched_barrier(0);
      __builtin_amdgcn_s_barrier();
    }
  }

#pragma unroll
  for (int m = 0; m < 4; ++m) {
    int row = row0 + wm * 64 + m * 16 + lh * 4;
#pragma unroll
    for (int n = 0; n < 4; ++n) {
      int col = col0 + wn * 64 + n * 16 + l16;
      float bv = bias[col];
#pragma unroll
      for (int r = 0; r < 4; ++r)
        H[(size_t)(row + r) * 512 + col] = acc[m][n][r] * WDESCALE + bv;
    }
  }
}

// ---------------------------------------------------------------------------
// Plain fp16 GEMM: C[M][N] = A[M][K] * BT[N][K]^T * outscale + bias[N]
// ---------------------------------------------------------------------------
template <bool OUT_HALF>
__global__ __launch_bounds__(256)
void gemm_tn(const _Float16* __restrict__ A, const _Float16* __restrict__ BT,
             const float* __restrict__ bias, void* __restrict__ C,
             int M, int N, int K, int nbn_log2, int nwg, float outscale) {
  __shared__ __align__(16) _Float16 Ash[128 * 64];
  __shared__ __align__(16) _Float16 Bsh[128 * 64];
  int lin = blockIdx.x;
  int q = nwg >> 3;
  int wg = (lin & 7) * q + (lin >> 3);
  int bn = wg & ((1 << nbn_log2) - 1);
  int bm = wg >> nbn_log2;
  int row0 = bm * 128, col0 = bn * 128;
  int tid = threadIdx.x, lane = tid & 63, wave = tid >> 6;
  int wm = wave >> 1, wn = wave & 1;
  int l16 = lane & 15, lh = lane >> 4;
  int sr = lane >> 3;
  int sc = ((lane & 7) * 8) ^ (sr << 3);

  f32x4 acc[4][4];
#pragma unroll
  for (int m = 0; m < 4; ++m)
#pragma unroll
    for (int n = 0; n < 4; ++n) acc[m][n] = (f32x4){0.f, 0.f, 0.f, 0.f};

  for (int kk0 = 0; kk0 < K; kk0 += 64) {
    const _Float16* Ag = A + (size_t)row0 * K + kk0;
    const _Float16* Bg = BT + (size_t)col0 * K + kk0;
#pragma unroll
    for (int it = 0; it < 4; ++it) {
      int chunk = it * 4 + wave;
      int r = chunk * 8 + sr;
      gload_lds16(Ag + (size_t)r * K + sc, Ash + chunk * 512);
      gload_lds16(Bg + (size_t)r * K + sc, Bsh + chunk * 512);
    }
    __syncthreads();
#pragma unroll
    for (int kc = 0; kc < 2; ++kc) {
      f16x8 af[4], bf[4];
#pragma unroll
      for (int m = 0; m < 4; ++m)
        af[m] = *(const f16x8*)&Ash[swz(wm * 64 + m * 16 + l16, kc * 32 + lh * 8)];
#pragma unroll
      for (int n = 0; n < 4; ++n)
        bf[n] = *(const f16x8*)&Bsh[swz(wn * 64 + n * 16 + l16, kc * 32 + lh * 8)];
#pragma unroll
      for (int m = 0; m < 4; ++m)
#pragma unroll
        for (int n = 0; n < 4; ++n)
          acc[m][n] = __builtin_amdgcn_mfma_f32_16x16x32_f16(af[m], bf[n], acc[m][n], 0, 0, 0);
    }
    __syncthreads();
  }

#pragma unroll
  for (int m = 0; m < 4; ++m) {
    int row = row0 + wm * 64 + m * 16 + lh * 4;
#pragma unroll
    for (int n = 0; n < 4; ++n) {
      int col = col0 + wn * 64 + n * 16 + l16;
      float bv = bias[col];
#pragma unroll
      for (int r = 0; r < 4; ++r) {
        float v = acc[m][n][r] * outscale + bv;
        if (OUT_HALF)
          ((_Float16*)C)[(size_t)(row + r) * N + col] = cvh(v);
        else
          ((float*)C)[(size_t)(row + r) * N + col] = v;
      }
    }
  }
}

// ---------------------------------------------------------------------------
extern "C" void kernel_launch(void* const* d_in, const int* in_sizes, int n_in,
                              void* d_out, int out_size, void* d_ws, size_t ws_size,
                              hipStream_t stream) {
  const float* x  = (const float*)d_in[0];
  const float* a0 = (const float*)d_in[1];
  const float* s0 = (const float*)d_in[2];
  const float* b0 = (const float*)d_in[3];
  const float* a1 = (const float*)d_in[4];
  const float* s1 = (const float*)d_in[5];
  const float* b1 = (const float*)d_in[6];
  const float* W  = (const float*)d_in[7];
  const float* bb = (const float*)d_in[8];

  const int Bn = 16384, D = 512, KK = 3584, DOUT = 256;

  char* p = (char*)d_ws;
  _Float16* Afeat = (_Float16*)p;                 // [16384][3584] fp16 (layer-2 feats)
  _Float16* Wh0   = (_Float16*)p;                 // aliased: dead once gemm_l1 done
  _Float16* Wl0   = (_Float16*)(p + 3670016);
  p += (size_t)Bn * KK * 2;                       // 117,440,512
  float*    h     = (float*)p;                    // fp32 h; later ghalf (fp16)
  _Float16* ghalf = (_Float16*)p;
  p += (size_t)Bn * D * 4;                        // 33,554,432
  _Float16* Wh1   = (_Float16*)p; p += (size_t)D * KK * 2;   // 3,670,016
  _Float16* WpT   = (_Float16*)p; p += (size_t)DOUT * D * 2; // 262,144
  float*    biasv = (float*)p;    p += 2 * D * 4;            // 4,096

  prep_weights<true ><<<dim3(512), dim3(512), 0, stream>>>(a0, s0, b0, Wh0, Wl0, biasv);
  prep_weights<false><<<dim3(512), dim3(512), 0, stream>>>(a1, s1, b1, Wh1, nullptr, biasv + 512);
  cvt_half_k<<<dim3(512), dim3(256), 0, stream>>>(W, WpT, DOUT * D);

  // layer 1: fused featurize + split-fp16 GEMM, pipelined -> h (fp32, ~exact)
  gemm_l1<<<dim3(256), dim3(512), 0, stream>>>(x, Wh0, Wl0, biasv, h);

  // layer 2: featurize h -> fp16, plain fp16 GEMM -> g (fp16)
  featurize_k<<<dim3(Bn * D / 256), dim3(256), 0, stream>>>(h, Afeat, Bn * D);
  gemm_tn<true><<<dim3(512), dim3(256), 0, stream>>>(Afeat, Wh1, biasv + 512, ghalf,
                                                     Bn, D, KK, 2, 512, WDESCALE);

  // projection
  gemm_tn<false><<<dim3(256), dim3(256), 0, stream>>>(ghalf, WpT, bb, (float*)d_out,
                                                      Bn, DOUT, D, 1, 256, PDESCALE);
}

// Round 5
// 454.756 us; speedup vs baseline: 1.0666x; 1.0666x over previous
//
#include <hip/hip_runtime.h>

typedef _Float16 f16x8 __attribute__((ext_vector_type(8)));
typedef float f32x4 __attribute__((ext_vector_type(4)));

#define EXP_CLIP 10.0f
#define FEPS 1e-6f
#define WSCALE 16384.0f      // 2^14 weight prescale (kills fp16-denorm weights)
#define WDESCALE (1.0f/16384.0f)
#define PSCALE 1024.0f       // proj weight prescale
#define PDESCALE (1.0f/1024.0f)

__device__ __forceinline__ _Float16 cvh(float v) {
  v = fminf(fmaxf(v, -60000.f), 60000.f);
  return (_Float16)v;
}

__device__ __forceinline__ void gload_lds16(const void* g, void* l) {
  __builtin_amdgcn_global_load_lds(
      (const __attribute__((address_space(1))) void*)g,
      (__attribute__((address_space(3))) void*)l, 16, 0, 0);
}

// XOR-swizzled LDS offset (half units) for a [*][64]-half tile.
__device__ __forceinline__ int swz(int row, int colh) {
  return row * 64 + (colh ^ ((row & 7) << 3));
}

__device__ __forceinline__ float prim_eval(int kp, float x) {
  switch (kp) {
    case 0: return x;
    case 1: return x * x;
    case 2: return x * x * x;
    case 3: return __expf(fminf(fmaxf(x, -EXP_CLIP), EXP_CLIP));
    case 4: return __logf(fabsf(x) + FEPS);
    case 5: return x / (x * x + FEPS);
    default: return __sinf(x);
  }
}

// ---------------------------------------------------------------------------
// Prep: per (layer, j) block, 512 threads over i.
// ---------------------------------------------------------------------------
template <bool EMIT_LO>
__global__ __launch_bounds__(512)
void prep_weights(const float* __restrict__ alphas, const float* __restrict__ scale,
                  const float* __restrict__ bias, _Float16* __restrict__ Wh,
                  _Float16* __restrict__ Wl, float* __restrict__ biasvec) {
  int j = blockIdx.x;
  int i = threadIdx.x;
  size_t base = ((size_t)i * 512 + j) * 8;
  float a[8];
#pragma unroll
  for (int k = 0; k < 8; ++k) a[k] = alphas[base + k];
  float m = a[0];
#pragma unroll
  for (int k = 1; k < 8; ++k) m = fmaxf(m, a[k]);
  float e[8], sum = 0.f;
#pragma unroll
  for (int k = 0; k < 8; ++k) { e[k] = __expf(a[k] - m); sum += e[k]; }
  float inv = 1.f / sum;
  float bp = 0.f;
#pragma unroll
  for (int k = 1; k < 8; ++k) {
    float w = e[k] * inv;
    float ws = fminf(fmaxf(w * scale[base + k] * WSCALE, -60000.f), 60000.f);
    _Float16 wh = (_Float16)ws;
    size_t o = (size_t)j * 3584 + (size_t)(k - 1) * 512 + i;
    Wh[o] = wh;
    if (EMIT_LO) Wl[o] = (_Float16)(ws - (float)wh);
    bp += w * bias[base + k];
  }
  __shared__ float red[512];
  red[i] = bp;
  __syncthreads();
  for (int off = 256; off > 0; off >>= 1) {
    if (i < off) red[i] += red[i + off];
    __syncthreads();
  }
  if (i == 0) biasvec[j] = red[0];
}

// ---------------------------------------------------------------------------
// Pre-featurize x -> Fhi/Flo [16384][3584] fp16 (hi = fp16(f), lo = f - hi).
// 8 elems/thread, coalesced float4 loads and f16x8 stores.
// ---------------------------------------------------------------------------
__global__ __launch_bounds__(256)
void featurize_hilo(const float* __restrict__ in, _Float16* __restrict__ hi,
                    _Float16* __restrict__ lo) {
  int t = blockIdx.x * 256 + threadIdx.x;    // 16384*64 threads
  int b = t >> 6, g = (t & 63) * 8;
  const float* xp = in + (size_t)b * 512 + g;
  float4 a = *(const float4*)xp;
  float4 c = *(const float4*)(xp + 4);
  float xv[8] = {a.x, a.y, a.z, a.w, c.x, c.y, c.z, c.w};
  _Float16* oh = hi + (size_t)b * 3584 + g;
  _Float16* ol = lo + (size_t)b * 3584 + g;
#pragma unroll
  for (int kp = 0; kp < 7; ++kp) {
    f16x8 hv, lv;
#pragma unroll
    for (int e = 0; e < 8; ++e) {
      float f = prim_eval(kp, xv[e]);
      _Float16 fh = (_Float16)f;
      hv[e] = fh;
      lv[e] = (_Float16)(f - (float)fh);
    }
    *(f16x8*)&oh[kp * 512] = hv;
    *(f16x8*)&ol[kp * 512] = lv;
  }
}

// ---------------------------------------------------------------------------
// Featurize (layer-2 input): h [rows][512] fp32 -> out [rows][3584] fp16.
// 8 elems/thread, vectorized.
// ---------------------------------------------------------------------------
__global__ __launch_bounds__(256)
void featurize8(const float* __restrict__ in, _Float16* __restrict__ out) {
  int t = blockIdx.x * 256 + threadIdx.x;    // 16384*64 threads
  int b = t >> 6, g = (t & 63) * 8;
  const float* xp = in + (size_t)b * 512 + g;
  float4 a = *(const float4*)xp;
  float4 c = *(const float4*)(xp + 4);
  float xv[8] = {a.x, a.y, a.z, a.w, c.x, c.y, c.z, c.w};
  _Float16* o = out + (size_t)b * 3584 + g;
#pragma unroll
  for (int kp = 0; kp < 7; ++kp) {
    f16x8 v;
#pragma unroll
    for (int e = 0; e < 8; ++e) v[e] = cvh(prim_eval(kp, xv[e]));
    *(f16x8*)&o[kp * 512] = v;
  }
}

__global__ __launch_bounds__(256)
void cvt_half_k(const float* __restrict__ in, _Float16* __restrict__ out, int n) {
  int idx = blockIdx.x * 256 + threadIdx.x;
  if (idx < n) out[idx] = (_Float16)(in[idx] * PSCALE);
}

// ---------------------------------------------------------------------------
// Layer-1 GEMM (pipeline A): pure 3-term split-fp16 GEMM on pre-featurized
// A (Fhi/Flo). Structure = proven gemm_tn (128x128, BK=64, 4 waves, 2 blk/CU),
// swizzled LDS, gload_lds staging for all four tiles.
// ---------------------------------------------------------------------------
__global__ __launch_bounds__(256)
void gemm_l1_pre(const _Float16* __restrict__ Fhi, const _Float16* __restrict__ Flo,
                 const _Float16* __restrict__ Wh, const _Float16* __restrict__ Wl,
                 const float* __restrict__ bias, float* __restrict__ H) {
  __shared__ __align__(16) _Float16 AhS[128 * 64];
  __shared__ __align__(16) _Float16 AlS[128 * 64];
  __shared__ __align__(16) _Float16 BhS[128 * 64];
  __shared__ __align__(16) _Float16 BlS[128 * 64];
  const int K = 3584;
  int lin = blockIdx.x;                 // 512 blocks
  int wg = (lin & 7) * 64 + (lin >> 3); // XCD-contiguous remap
  int bn = wg & 3, bm = wg >> 2;        // bn fast => 4 bn-blocks share A panel in L2
  int row0 = bm * 128, col0 = bn * 128;
  int tid = threadIdx.x, lane = tid & 63, wave = tid >> 6;
  int wm = wave >> 1, wn = wave & 1;
  int l16 = lane & 15, lh = lane >> 4;
  int sr = lane >> 3, sc = ((lane & 7) * 8) ^ (sr << 3);  // pre-swizzled src col

  f32x4 acc[4][4];
#pragma unroll
  for (int m = 0; m < 4; ++m)
#pragma unroll
    for (int n = 0; n < 4; ++n) acc[m][n] = (f32x4){0.f, 0.f, 0.f, 0.f};

  for (int kk0 = 0; kk0 < K; kk0 += 64) {
    const _Float16* Agh = Fhi + (size_t)row0 * K + kk0;
    const _Float16* Agl = Flo + (size_t)row0 * K + kk0;
    const _Float16* Bgh = Wh + (size_t)col0 * K + kk0;
    const _Float16* Bgl = Wl + (size_t)col0 * K + kk0;
#pragma unroll
    for (int it = 0; it < 4; ++it) {
      int chunk = it * 4 + wave;
      int r = chunk * 8 + sr;
      size_t go = (size_t)r * K + sc;
      gload_lds16(Agh + go, AhS + chunk * 512);
      gload_lds16(Agl + go, AlS + chunk * 512);
      gload_lds16(Bgh + go, BhS + chunk * 512);
      gload_lds16(Bgl + go, BlS + chunk * 512);
    }
    __syncthreads();
#pragma unroll
    for (int kc = 0; kc < 2; ++kc) {
      f16x8 ah[4], al[4];
#pragma unroll
      for (int m = 0; m < 4; ++m) {
        int off = swz(wm * 64 + m * 16 + l16, kc * 32 + lh * 8);
        ah[m] = *(const f16x8*)&AhS[off];
        al[m] = *(const f16x8*)&AlS[off];
      }
#pragma unroll
      for (int n = 0; n < 4; ++n) {
        int ob = swz(wn * 64 + n * 16 + l16, kc * 32 + lh * 8);
        f16x8 bh = *(const f16x8*)&BhS[ob];
        f16x8 bl = *(const f16x8*)&BlS[ob];
#pragma unroll
        for (int m = 0; m < 4; ++m) {
          acc[m][n] = __builtin_amdgcn_mfma_f32_16x16x32_f16(ah[m], bh, acc[m][n], 0, 0, 0);
          acc[m][n] = __builtin_amdgcn_mfma_f32_16x16x32_f16(al[m], bh, acc[m][n], 0, 0, 0);
          acc[m][n] = __builtin_amdgcn_mfma_f32_16x16x32_f16(ah[m], bl, acc[m][n], 0, 0, 0);
        }
      }
    }
    __syncthreads();
  }

#pragma unroll
  for (int m = 0; m < 4; ++m) {
    int row = row0 + wm * 64 + m * 16 + lh * 4;
#pragma unroll
    for (int n = 0; n < 4; ++n) {
      int col = col0 + wn * 64 + n * 16 + l16;
      float bv = bias[col];
#pragma unroll
      for (int r = 0; r < 4; ++r)
        H[(size_t)(row + r) * 512 + col] = acc[m][n][r] * WDESCALE + bv;
    }
  }
}

// ---------------------------------------------------------------------------
// Layer-1 fused GEMM (pipeline B fallback, round-3 proven): featurize in-loop.
// ---------------------------------------------------------------------------
__global__ __launch_bounds__(256, 2)
void gemm_l1_fused(const float* __restrict__ X, const _Float16* __restrict__ Wh,
                   const _Float16* __restrict__ Wl, const float* __restrict__ bias,
                   float* __restrict__ H) {
  __shared__ __align__(16) _Float16 AhS[128 * 64];
  __shared__ __align__(16) _Float16 AlS[128 * 64];
  __shared__ __align__(16) _Float16 BhS[128 * 64];
  __shared__ __align__(16) _Float16 BlS[128 * 64];
  const int K = 3584;
  int lin = blockIdx.x;
  int wg = (lin & 7) * 64 + (lin >> 3);
  int bn = wg & 3, bm = wg >> 2;
  int row0 = bm * 128, col0 = bn * 128;
  int tid = threadIdx.x, lane = tid & 63, wave = tid >> 6;
  int wm = wave >> 1, wn = wave & 1;
  int l16 = lane & 15, lh = lane >> 4;
  int sr = lane >> 3, sc = ((lane & 7) * 8) ^ (sr << 3);
  int ar = tid >> 3, ac = (tid & 7) * 8;

  f32x4 acc[4][4];
#pragma unroll
  for (int m = 0; m < 4; ++m)
#pragma unroll
    for (int n = 0; n < 4; ++n) acc[m][n] = (f32x4){0.f, 0.f, 0.f, 0.f};

#pragma unroll 1
  for (int kk0 = 0; kk0 < K; kk0 += 64) {
    int kp = kk0 >> 9, i0 = kk0 & 511;
    const _Float16* Bgh = Wh + (size_t)col0 * K + kk0;
    const _Float16* Bgl = Wl + (size_t)col0 * K + kk0;
#pragma unroll
    for (int it = 0; it < 4; ++it) {
      int chunk = it * 4 + wave;
      int r = chunk * 8 + sr;
      gload_lds16(Bgh + (size_t)r * K + sc, BhS + chunk * 512);
      gload_lds16(Bgl + (size_t)r * K + sc, BlS + chunk * 512);
    }
#pragma unroll
    for (int it = 0; it < 4; ++it) {
      int r = it * 32 + ar;
      const float* xp = X + (size_t)(row0 + r) * 512 + i0 + ac;
      float4 x01 = *(const float4*)xp;
      float4 x23 = *(const float4*)(xp + 4);
      float xv[8] = {x01.x, x01.y, x01.z, x01.w, x23.x, x23.y, x23.z, x23.w};
      f16x8 hv, lv;
#pragma unroll
      for (int e = 0; e < 8; ++e) {
        float f = prim_eval(kp, xv[e]);
        _Float16 fh = (_Float16)f;
        hv[e] = fh;
        lv[e] = (_Float16)(f - (float)fh);
      }
      int wo = swz(r, ac);
      *(f16x8*)&AhS[wo] = hv;
      *(f16x8*)&AlS[wo] = lv;
    }
    __syncthreads();
#pragma unroll
    for (int kc = 0; kc < 2; ++kc) {
      f16x8 ah[4], al[4];
#pragma unroll
      for (int m = 0; m < 4; ++m) {
        int off = swz(wm * 64 + m * 16 + l16, kc * 32 + lh * 8);
        ah[m] = *(const f16x8*)&AhS[off];
        al[m] = *(const f16x8*)&AlS[off];
      }
#pragma unroll
      for (int n = 0; n < 4; ++n) {
        int ob = swz(wn * 64 + n * 16 + l16, kc * 32 + lh * 8);
        f16x8 bh = *(const f16x8*)&BhS[ob];
        f16x8 bl = *(const f16x8*)&BlS[ob];
#pragma unroll
        for (int m = 0; m < 4; ++m) {
          acc[m][n] = __builtin_amdgcn_mfma_f32_16x16x32_f16(ah[m], bh, acc[m][n], 0, 0, 0);
          acc[m][n] = __builtin_amdgcn_mfma_f32_16x16x32_f16(al[m], bh, acc[m][n], 0, 0, 0);
          acc[m][n] = __builtin_amdgcn_mfma_f32_16x16x32_f16(ah[m], bl, acc[m][n], 0, 0, 0);
        }
      }
    }
    __syncthreads();
  }

#pragma unroll
  for (int m = 0; m < 4; ++m) {
    int row = row0 + wm * 64 + m * 16 + lh * 4;
#pragma unroll
    for (int n = 0; n < 4; ++n) {
      int col = col0 + wn * 64 + n * 16 + l16;
      float bv = bias[col];
#pragma unroll
      for (int r = 0; r < 4; ++r)
        H[(size_t)(row + r) * 512 + col] = acc[m][n][r] * WDESCALE + bv;
    }
  }
}

// ---------------------------------------------------------------------------
// Plain fp16 GEMM: C[M][N] = A[M][K] * BT[N][K]^T * outscale + bias[N]
// ---------------------------------------------------------------------------
template <bool OUT_HALF>
__global__ __launch_bounds__(256)
void gemm_tn(const _Float16* __restrict__ A, const _Float16* __restrict__ BT,
             const float* __restrict__ bias, void* __restrict__ C,
             int M, int N, int K, int nbn_log2, int nwg, float outscale) {
  __shared__ __align__(16) _Float16 Ash[128 * 64];
  __shared__ __align__(16) _Float16 Bsh[128 * 64];
  int lin = blockIdx.x;
  int q = nwg >> 3;
  int wg = (lin & 7) * q + (lin >> 3);
  int bn = wg & ((1 << nbn_log2) - 1);
  int bm = wg >> nbn_log2;
  int row0 = bm * 128, col0 = bn * 128;
  int tid = threadIdx.x, lane = tid & 63, wave = tid >> 6;
  int wm = wave >> 1, wn = wave & 1;
  int l16 = lane & 15, lh = lane >> 4;
  int sr = lane >> 3;
  int sc = ((lane & 7) * 8) ^ (sr << 3);

  f32x4 acc[4][4];
#pragma unroll
  for (int m = 0; m < 4; ++m)
#pragma unroll
    for (int n = 0; n < 4; ++n) acc[m][n] = (f32x4){0.f, 0.f, 0.f, 0.f};

  for (int kk0 = 0; kk0 < K; kk0 += 64) {
    const _Float16* Ag = A + (size_t)row0 * K + kk0;
    const _Float16* Bg = BT + (size_t)col0 * K + kk0;
#pragma unroll
    for (int it = 0; it < 4; ++it) {
      int chunk = it * 4 + wave;
      int r = chunk * 8 + sr;
      gload_lds16(Ag + (size_t)r * K + sc, Ash + chunk * 512);
      gload_lds16(Bg + (size_t)r * K + sc, Bsh + chunk * 512);
    }
    __syncthreads();
#pragma unroll
    for (int kc = 0; kc < 2; ++kc) {
      f16x8 af[4], bf[4];
#pragma unroll
      for (int m = 0; m < 4; ++m)
        af[m] = *(const f16x8*)&Ash[swz(wm * 64 + m * 16 + l16, kc * 32 + lh * 8)];
#pragma unroll
      for (int n = 0; n < 4; ++n)
        bf[n] = *(const f16x8*)&Bsh[swz(wn * 64 + n * 16 + l16, kc * 32 + lh * 8)];
#pragma unroll
      for (int m = 0; m < 4; ++m)
#pragma unroll
        for (int n = 0; n < 4; ++n)
          acc[m][n] = __builtin_amdgcn_mfma_f32_16x16x32_f16(af[m], bf[n], acc[m][n], 0, 0, 0);
    }
    __syncthreads();
  }

#pragma unroll
  for (int m = 0; m < 4; ++m) {
    int row = row0 + wm * 64 + m * 16 + lh * 4;
#pragma unroll
    for (int n = 0; n < 4; ++n) {
      int col = col0 + wn * 64 + n * 16 + l16;
      float bv = bias[col];
#pragma unroll
      for (int r = 0; r < 4; ++r) {
        float v = acc[m][n][r] * outscale + bv;
        if (OUT_HALF)
          ((_Float16*)C)[(size_t)(row + r) * N + col] = cvh(v);
        else
          ((float*)C)[(size_t)(row + r) * N + col] = v;
      }
    }
  }
}

// ---------------------------------------------------------------------------
extern "C" void kernel_launch(void* const* d_in, const int* in_sizes, int n_in,
                              void* d_out, int out_size, void* d_ws, size_t ws_size,
                              hipStream_t stream) {
  const float* x  = (const float*)d_in[0];
  const float* a0 = (const float*)d_in[1];
  const float* s0 = (const float*)d_in[2];
  const float* b0 = (const float*)d_in[3];
  const float* a1 = (const float*)d_in[4];
  const float* s1 = (const float*)d_in[5];
  const float* b1 = (const float*)d_in[6];
  const float* W  = (const float*)d_in[7];
  const float* bb = (const float*)d_in[8];

  const int Bn = 16384, D = 512, KK = 3584, DOUT = 256;
  const size_t szF = (size_t)Bn * KK * 2;   // 117,440,512
  const size_t szH = (size_t)Bn * D * 4;    //  33,554,432
  const size_t szW = (size_t)D * KK * 2;    //   3,670,016
  const size_t szP = (size_t)DOUT * D * 2;  //     262,144
  const size_t needA = 2 * szF + szH + 3 * szW + szP + 4096;  // ~279.7 MB

  if (ws_size >= needA) {
    // ---- pipeline A: pre-featurized layer-1 ----
    char* p = (char*)d_ws;
    _Float16* Fhi   = (_Float16*)p; p += szF;   // also reused as layer-2 Afeat
    _Float16* Flo   = (_Float16*)p; p += szF;
    float*    h     = (float*)p;
    _Float16* ghalf = (_Float16*)p; p += szH;
    _Float16* Wh0   = (_Float16*)p; p += szW;
    _Float16* Wl0   = (_Float16*)p; p += szW;
    _Float16* Wh1   = (_Float16*)p; p += szW;
    _Float16* WpT   = (_Float16*)p; p += szP;
    float*    biasv = (float*)p;

    prep_weights<true ><<<dim3(512), dim3(512), 0, stream>>>(a0, s0, b0, Wh0, Wl0, biasv);
    prep_weights<false><<<dim3(512), dim3(512), 0, stream>>>(a1, s1, b1, Wh1, nullptr, biasv + 512);
    cvt_half_k<<<dim3(512), dim3(256), 0, stream>>>(W, WpT, DOUT * D);

    featurize_hilo<<<dim3(Bn * 64 / 256), dim3(256), 0, stream>>>(x, Fhi, Flo);
    gemm_l1_pre<<<dim3(512), dim3(256), 0, stream>>>(Fhi, Flo, Wh0, Wl0, biasv, h);

    featurize8<<<dim3(Bn * 64 / 256), dim3(256), 0, stream>>>(h, Fhi);
    gemm_tn<true><<<dim3(512), dim3(256), 0, stream>>>(Fhi, Wh1, biasv + 512, ghalf,
                                                       Bn, D, KK, 2, 512, WDESCALE);

    gemm_tn<false><<<dim3(256), dim3(256), 0, stream>>>(ghalf, WpT, bb, (float*)d_out,
                                                        Bn, DOUT, D, 1, 256, PDESCALE);
  } else {
    // ---- pipeline B (round-3 fallback): fused featurize layer-1 ----
    char* p = (char*)d_ws;
    _Float16* Afeat = (_Float16*)p;
    _Float16* Wh0   = (_Float16*)p;
    _Float16* Wl0   = (_Float16*)(p + szW);
    p += szF;
    float*    h     = (float*)p;
    _Float16* ghalf = (_Float16*)p;
    p += szH;
    _Float16* Wh1   = (_Float16*)p; p += szW;
    _Float16* WpT   = (_Float16*)p; p += szP;
    float*    biasv = (float*)p;

    prep_weights<true ><<<dim3(512), dim3(512), 0, stream>>>(a0, s0, b0, Wh0, Wl0, biasv);
    prep_weights<false><<<dim3(512), dim3(512), 0, stream>>>(a1, s1, b1, Wh1, nullptr, biasv + 512);
    cvt_half_k<<<dim3(512), dim3(256), 0, stream>>>(W, WpT, DOUT * D);

    gemm_l1_fused<<<dim3(512), dim3(256), 0, stream>>>(x, Wh0, Wl0, biasv, h);

    featurize8<<<dim3(Bn * 64 / 256), dim3(256), 0, stream>>>(h, Afeat);
    gemm_tn<true><<<dim3(512), dim3(256), 0, stream>>>(Afeat, Wh1, biasv + 512, ghalf,
                                                       Bn, D, KK, 2, 512, WDESCALE);

    gemm_tn<false><<<dim3(256), dim3(256), 0, stream>>>(ghalf, WpT, bb, (float*)d_out,
                                                        Bn, DOUT, D, 1, 256, PDESCALE);
  }
}

// Round 6
// 348.007 us; speedup vs baseline: 1.3937x; 1.3067x over previous
//
#include <hip/hip_runtime.h>
#include <string.h>

typedef _Float16 f16x8 __attribute__((ext_vector_type(8)));
typedef float f32x4 __attribute__((ext_vector_type(4)));

#define EXP_CLIP 10.0f
#define FEPS 1e-6f
#define WSCALE 16384.0f      // 2^14 weight prescale (kills fp16-denorm weights)
#define WDESCALE (1.0f/16384.0f)
#define PSCALE 1024.0f       // proj weight prescale
#define PDESCALE (1.0f/1024.0f)

__device__ __forceinline__ _Float16 cvh(float v) {
  v = fminf(fmaxf(v, -60000.f), 60000.f);
  return (_Float16)v;
}

__device__ __forceinline__ void gload_lds16(const void* g, void* l) {
  __builtin_amdgcn_global_load_lds(
      (const __attribute__((address_space(1))) void*)g,
      (__attribute__((address_space(3))) void*)l, 16, 0, 0);
}

// XOR-swizzled LDS offset (half units) for a [*][64]-half tile.
__device__ __forceinline__ int swz(int row, int colh) {
  return row * 64 + (colh ^ ((row & 7) << 3));
}

__device__ __forceinline__ float prim_eval(int kp, float x) {
  switch (kp) {
    case 0: return x;
    case 1: return x * x;
    case 2: return x * x * x;
    case 3: return __expf(fminf(fmaxf(x, -EXP_CLIP), EXP_CLIP));
    case 4: return __logf(fabsf(x) + FEPS);
    case 5: return x / (x * x + FEPS);
    default: return __sinf(x);
  }
}

// e5m2 encode (RNE) of a small residual: fp16 bits -> top byte with rounding.
__device__ __forceinline__ unsigned char enc_e5m2(float lo) {
  _Float16 lh = (_Float16)lo;
  unsigned short u;
  memcpy(&u, &lh, 2);
  unsigned t = (unsigned)u + 0x7Fu + ((u >> 8) & 1u);
  return (unsigned char)(t >> 8);
}

// ---------------------------------------------------------------------------
// Prep: per (layer, j) block, 512 threads over i.
// ---------------------------------------------------------------------------
template <bool EMIT_LO>
__global__ __launch_bounds__(512)
void prep_weights(const float* __restrict__ alphas, const float* __restrict__ scale,
                  const float* __restrict__ bias, _Float16* __restrict__ Wh,
                  _Float16* __restrict__ Wl, float* __restrict__ biasvec) {
  int j = blockIdx.x;
  int i = threadIdx.x;
  size_t base = ((size_t)i * 512 + j) * 8;
  float a[8];
#pragma unroll
  for (int k = 0; k < 8; ++k) a[k] = alphas[base + k];
  float m = a[0];
#pragma unroll
  for (int k = 1; k < 8; ++k) m = fmaxf(m, a[k]);
  float e[8], sum = 0.f;
#pragma unroll
  for (int k = 0; k < 8; ++k) { e[k] = __expf(a[k] - m); sum += e[k]; }
  float inv = 1.f / sum;
  float bp = 0.f;
#pragma unroll
  for (int k = 1; k < 8; ++k) {
    float w = e[k] * inv;
    float ws = fminf(fmaxf(w * scale[base + k] * WSCALE, -60000.f), 60000.f);
    _Float16 wh = (_Float16)ws;
    size_t o = (size_t)j * 3584 + (size_t)(k - 1) * 512 + i;
    Wh[o] = wh;
    if (EMIT_LO) Wl[o] = (_Float16)(ws - (float)wh);
    bp += w * bias[base + k];
  }
  __shared__ float red[512];
  red[i] = bp;
  __syncthreads();
  for (int off = 256; off > 0; off >>= 1) {
    if (i < off) red[i] += red[i + off];
    __syncthreads();
  }
  if (i == 0) biasvec[j] = red[0];
}

// ---------------------------------------------------------------------------
// Pre-featurize x -> Fhi fp16 + FloB e5m2-byte, both [16384][3584].
// ---------------------------------------------------------------------------
__global__ __launch_bounds__(256)
void featurize_hilo(const float* __restrict__ in, _Float16* __restrict__ hi,
                    unsigned char* __restrict__ loB) {
  int t = blockIdx.x * 256 + threadIdx.x;    // 16384*64 threads
  int b = t >> 6, g = (t & 63) * 8;
  const float* xp = in + (size_t)b * 512 + g;
  float4 a = *(const float4*)xp;
  float4 c = *(const float4*)(xp + 4);
  float xv[8] = {a.x, a.y, a.z, a.w, c.x, c.y, c.z, c.w};
  _Float16* oh = hi + (size_t)b * 3584 + g;
  unsigned char* ol = loB + (size_t)b * 3584 + g;
#pragma unroll
  for (int kp = 0; kp < 7; ++kp) {
    f16x8 hv;
    unsigned long long lb = 0;
#pragma unroll
    for (int e = 0; e < 8; ++e) {
      float f = prim_eval(kp, xv[e]);
      _Float16 fh = (_Float16)f;
      hv[e] = fh;
      lb |= (unsigned long long)enc_e5m2(f - (float)fh) << (8 * e);
    }
    *(f16x8*)&oh[kp * 512] = hv;
    *(unsigned long long*)&ol[kp * 512] = lb;
  }
}

// ---------------------------------------------------------------------------
// Featurize (layer-2 input): h [rows][512] fp32 -> out [rows][3584] fp16.
// ---------------------------------------------------------------------------
__global__ __launch_bounds__(256)
void featurize8(const float* __restrict__ in, _Float16* __restrict__ out) {
  int t = blockIdx.x * 256 + threadIdx.x;
  int b = t >> 6, g = (t & 63) * 8;
  const float* xp = in + (size_t)b * 512 + g;
  float4 a = *(const float4*)xp;
  float4 c = *(const float4*)(xp + 4);
  float xv[8] = {a.x, a.y, a.z, a.w, c.x, c.y, c.z, c.w};
  _Float16* o = out + (size_t)b * 3584 + g;
#pragma unroll
  for (int kp = 0; kp < 7; ++kp) {
    f16x8 v;
#pragma unroll
    for (int e = 0; e < 8; ++e) v[e] = cvh(prim_eval(kp, xv[e]));
    *(f16x8*)&o[kp * 512] = v;
  }
}

__global__ __launch_bounds__(256)
void cvt_half_k(const float* __restrict__ in, _Float16* __restrict__ out, int n) {
  int idx = blockIdx.x * 256 + threadIdx.x;
  if (idx < n) out[idx] = (_Float16)(in[idx] * PSCALE);
}

// ---------------------------------------------------------------------------
// Layer-1 GEMM (pipeline A): 3-term split GEMM on pre-featurized A.
// A-hi fp16 (swizzled), A-lo e5m2 bytes (linear LDS, expanded in-loop),
// B-hi/B-lo fp16 (swizzled). 128x128, BK=64, 4 waves, 56 KB LDS (2 blk/CU).
// ---------------------------------------------------------------------------
__global__ __launch_bounds__(256)
void gemm_l1_pre(const _Float16* __restrict__ Fhi, const unsigned char* __restrict__ FloB,
                 const _Float16* __restrict__ Wh, const _Float16* __restrict__ Wl,
                 const float* __restrict__ bias, float* __restrict__ H) {
  __shared__ __align__(16) _Float16 AhS[128 * 64];       // 16 KB
  __shared__ __align__(16) unsigned char AlB[128 * 64];  //  8 KB
  __shared__ __align__(16) _Float16 BhS[128 * 64];       // 16 KB
  __shared__ __align__(16) _Float16 BlS[128 * 64];       // 16 KB
  const int K = 3584;
  int lin = blockIdx.x;                 // 512 blocks
  int wg = (lin & 7) * 64 + (lin >> 3); // XCD-contiguous remap
  int bn = wg & 3, bm = wg >> 2;        // bn fast: 4 col-blocks share A panel in XCD-L2
  int row0 = bm * 128, col0 = bn * 128;
  int tid = threadIdx.x, lane = tid & 63, wave = tid >> 6;
  int wm = wave >> 1, wn = wave & 1;
  int l16 = lane & 15, lh = lane >> 4;
  int sr = lane >> 3, sc = ((lane & 7) * 8) ^ (sr << 3);  // pre-swizzled src col (halves)
  int br = lane >> 2, bc = (lane & 3) * 16;               // byte-tile staging row/col

  f32x4 acc[4][4];
#pragma unroll
  for (int m = 0; m < 4; ++m)
#pragma unroll
    for (int n = 0; n < 4; ++n) acc[m][n] = (f32x4){0.f, 0.f, 0.f, 0.f};

  for (int kk0 = 0; kk0 < K; kk0 += 64) {
    const _Float16* Agh = Fhi + (size_t)row0 * K + kk0;
    const unsigned char* Agl = FloB + (size_t)row0 * K + kk0;
    const _Float16* Bgh = Wh + (size_t)col0 * K + kk0;
    const _Float16* Bgl = Wl + (size_t)col0 * K + kk0;
#pragma unroll
    for (int it = 0; it < 4; ++it) {
      int chunk = it * 4 + wave;          // 0..15
      int r = chunk * 8 + sr;
      size_t go = (size_t)r * K + sc;
      gload_lds16(Agh + go, AhS + chunk * 512);
      gload_lds16(Bgh + go, BhS + chunk * 512);
      gload_lds16(Bgl + go, BlS + chunk * 512);
    }
#pragma unroll
    for (int it = 0; it < 2; ++it) {
      int chunk = it * 4 + wave;          // 0..7, 16 rows each
      int r = chunk * 16 + br;
      gload_lds16(Agl + (size_t)r * K + bc, AlB + chunk * 1024);
    }
    __syncthreads();
#pragma unroll
    for (int kc = 0; kc < 2; ++kc) {
      f16x8 ah[4], al[4];
#pragma unroll
      for (int m = 0; m < 4; ++m) {
        int row = wm * 64 + m * 16 + l16;
        ah[m] = *(const f16x8*)&AhS[swz(row, kc * 32 + lh * 8)];
        // A-lo: 8 e5m2 bytes -> 8 fp16 (byte<<8)
        uint2 d = *(const uint2*)&AlB[row * 64 + kc * 32 + lh * 8];
        union { unsigned u[4]; f16x8 v; } ex;
        ex.u[0] = ((d.x << 8) & 0xFF00u) | ((d.x << 16) & 0xFF000000u);
        ex.u[1] = ((d.x >> 8) & 0xFF00u) | (d.x & 0xFF000000u);
        ex.u[2] = ((d.y << 8) & 0xFF00u) | ((d.y << 16) & 0xFF000000u);
        ex.u[3] = ((d.y >> 8) & 0xFF00u) | (d.y & 0xFF000000u);
        al[m] = ex.v;
      }
#pragma unroll
      for (int n = 0; n < 4; ++n) {
        int ob = swz(wn * 64 + n * 16 + l16, kc * 32 + lh * 8);
        f16x8 bh = *(const f16x8*)&BhS[ob];
        f16x8 bl = *(const f16x8*)&BlS[ob];
#pragma unroll
        for (int m = 0; m < 4; ++m) {
          acc[m][n] = __builtin_amdgcn_mfma_f32_16x16x32_f16(ah[m], bh, acc[m][n], 0, 0, 0);
          acc[m][n] = __builtin_amdgcn_mfma_f32_16x16x32_f16(al[m], bh, acc[m][n], 0, 0, 0);
          acc[m][n] = __builtin_amdgcn_mfma_f32_16x16x32_f16(ah[m], bl, acc[m][n], 0, 0, 0);
        }
      }
    }
    __syncthreads();
  }

#pragma unroll
  for (int m = 0; m < 4; ++m) {
    int row = row0 + wm * 64 + m * 16 + lh * 4;
#pragma unroll
    for (int n = 0; n < 4; ++n) {
      int col = col0 + wn * 64 + n * 16 + l16;
      float bv = bias[col];
#pragma unroll
      for (int r = 0; r < 4; ++r)
        H[(size_t)(row + r) * 512 + col] = acc[m][n][r] * WDESCALE + bv;
    }
  }
}

// ---------------------------------------------------------------------------
// Layer-1 fused GEMM (pipeline B fallback, proven): featurize in-loop.
// ---------------------------------------------------------------------------
__global__ __launch_bounds__(256, 2)
void gemm_l1_fused(const float* __restrict__ X, const _Float16* __restrict__ Wh,
                   const _Float16* __restrict__ Wl, const float* __restrict__ bias,
                   float* __restrict__ H) {
  __shared__ __align__(16) _Float16 AhS[128 * 64];
  __shared__ __align__(16) _Float16 AlS[128 * 64];
  __shared__ __align__(16) _Float16 BhS[128 * 64];
  __shared__ __align__(16) _Float16 BlS[128 * 64];
  const int K = 3584;
  int lin = blockIdx.x;
  int wg = (lin & 7) * 64 + (lin >> 3);
  int bn = wg & 3, bm = wg >> 2;
  int row0 = bm * 128, col0 = bn * 128;
  int tid = threadIdx.x, lane = tid & 63, wave = tid >> 6;
  int wm = wave >> 1, wn = wave & 1;
  int l16 = lane & 15, lh = lane >> 4;
  int sr = lane >> 3, sc = ((lane & 7) * 8) ^ (sr << 3);
  int ar = tid >> 3, ac = (tid & 7) * 8;

  f32x4 acc[4][4];
#pragma unroll
  for (int m = 0; m < 4; ++m)
#pragma unroll
    for (int n = 0; n < 4; ++n) acc[m][n] = (f32x4){0.f, 0.f, 0.f, 0.f};

#pragma unroll 1
  for (int kk0 = 0; kk0 < K; kk0 += 64) {
    int kp = kk0 >> 9, i0 = kk0 & 511;
    const _Float16* Bgh = Wh + (size_t)col0 * K + kk0;
    const _Float16* Bgl = Wl + (size_t)col0 * K + kk0;
#pragma unroll
    for (int it = 0; it < 4; ++it) {
      int chunk = it * 4 + wave;
      int r = chunk * 8 + sr;
      gload_lds16(Bgh + (size_t)r * K + sc, BhS + chunk * 512);
      gload_lds16(Bgl + (size_t)r * K + sc, BlS + chunk * 512);
    }
#pragma unroll
    for (int it = 0; it < 4; ++it) {
      int r = it * 32 + ar;
      const float* xp = X + (size_t)(row0 + r) * 512 + i0 + ac;
      float4 x01 = *(const float4*)xp;
      float4 x23 = *(const float4*)(xp + 4);
      float xv[8] = {x01.x, x01.y, x01.z, x01.w, x23.x, x23.y, x23.z, x23.w};
      f16x8 hv, lv;
#pragma unroll
      for (int e = 0; e < 8; ++e) {
        float f = prim_eval(kp, xv[e]);
        _Float16 fh = (_Float16)f;
        hv[e] = fh;
        lv[e] = (_Float16)(f - (float)fh);
      }
      int wo = swz(r, ac);
      *(f16x8*)&AhS[wo] = hv;
      *(f16x8*)&AlS[wo] = lv;
    }
    __syncthreads();
#pragma unroll
    for (int kc = 0; kc < 2; ++kc) {
      f16x8 ah[4], al[4];
#pragma unroll
      for (int m = 0; m < 4; ++m) {
        int off = swz(wm * 64 + m * 16 + l16, kc * 32 + lh * 8);
        ah[m] = *(const f16x8*)&AhS[off];
        al[m] = *(const f16x8*)&AlS[off];
      }
#pragma unroll
      for (int n = 0; n < 4; ++n) {
        int ob = swz(wn * 64 + n * 16 + l16, kc * 32 + lh * 8);
        f16x8 bh = *(const f16x8*)&BhS[ob];
        f16x8 bl = *(const f16x8*)&BlS[ob];
#pragma unroll
        for (int m = 0; m < 4; ++m) {
          acc[m][n] = __builtin_amdgcn_mfma_f32_16x16x32_f16(ah[m], bh, acc[m][n], 0, 0, 0);
          acc[m][n] = __builtin_amdgcn_mfma_f32_16x16x32_f16(al[m], bh, acc[m][n], 0, 0, 0);
          acc[m][n] = __builtin_amdgcn_mfma_f32_16x16x32_f16(ah[m], bl, acc[m][n], 0, 0, 0);
        }
      }
    }
    __syncthreads();
  }

#pragma unroll
  for (int m = 0; m < 4; ++m) {
    int row = row0 + wm * 64 + m * 16 + lh * 4;
#pragma unroll
    for (int n = 0; n < 4; ++n) {
      int col = col0 + wn * 64 + n * 16 + l16;
      float bv = bias[col];
#pragma unroll
      for (int r = 0; r < 4; ++r)
        H[(size_t)(row + r) * 512 + col] = acc[m][n][r] * WDESCALE + bv;
    }
  }
}

// ---------------------------------------------------------------------------
// Plain fp16 GEMM: C[M][N] = A[M][K] * BT[N][K]^T * outscale + bias[N]
// ---------------------------------------------------------------------------
template <bool OUT_HALF>
__global__ __launch_bounds__(256)
void gemm_tn(const _Float16* __restrict__ A, const _Float16* __restrict__ BT,
             const float* __restrict__ bias, void* __restrict__ C,
             int M, int N, int K, int nbn_log2, int nwg, float outscale) {
  __shared__ __align__(16) _Float16 Ash[128 * 64];
  __shared__ __align__(16) _Float16 Bsh[128 * 64];
  int lin = blockIdx.x;
  int q = nwg >> 3;
  int wg = (lin & 7) * q + (lin >> 3);
  int bn = wg & ((1 << nbn_log2) - 1);
  int bm = wg >> nbn_log2;
  int row0 = bm * 128, col0 = bn * 128;
  int tid = threadIdx.x, lane = tid & 63, wave = tid >> 6;
  int wm = wave >> 1, wn = wave & 1;
  int l16 = lane & 15, lh = lane >> 4;
  int sr = lane >> 3;
  int sc = ((lane & 7) * 8) ^ (sr << 3);

  f32x4 acc[4][4];
#pragma unroll
  for (int m = 0; m < 4; ++m)
#pragma unroll
    for (int n = 0; n < 4; ++n) acc[m][n] = (f32x4){0.f, 0.f, 0.f, 0.f};

  for (int kk0 = 0; kk0 < K; kk0 += 64) {
    const _Float16* Ag = A + (size_t)row0 * K + kk0;
    const _Float16* Bg = BT + (size_t)col0 * K + kk0;
#pragma unroll
    for (int it = 0; it < 4; ++it) {
      int chunk = it * 4 + wave;
      int r = chunk * 8 + sr;
      gload_lds16(Ag + (size_t)r * K + sc, Ash + chunk * 512);
      gload_lds16(Bg + (size_t)r * K + sc, Bsh + chunk * 512);
    }
    __syncthreads();
#pragma unroll
    for (int kc = 0; kc < 2; ++kc) {
      f16x8 af[4], bf[4];
#pragma unroll
      for (int m = 0; m < 4; ++m)
        af[m] = *(const f16x8*)&Ash[swz(wm * 64 + m * 16 + l16, kc * 32 + lh * 8)];
#pragma unroll
      for (int n = 0; n < 4; ++n)
        bf[n] = *(const f16x8*)&Bsh[swz(wn * 64 + n * 16 + l16, kc * 32 + lh * 8)];
#pragma unroll
      for (int m = 0; m < 4; ++m)
#pragma unroll
        for (int n = 0; n < 4; ++n)
          acc[m][n] = __builtin_amdgcn_mfma_f32_16x16x32_f16(af[m], bf[n], acc[m][n], 0, 0, 0);
    }
    __syncthreads();
  }

#pragma unroll
  for (int m = 0; m < 4; ++m) {
    int row = row0 + wm * 64 + m * 16 + lh * 4;
#pragma unroll
    for (int n = 0; n < 4; ++n) {
      int col = col0 + wn * 64 + n * 16 + l16;
      float bv = bias[col];
#pragma unroll
      for (int r = 0; r < 4; ++r) {
        float v = acc[m][n][r] * outscale + bv;
        if (OUT_HALF)
          ((_Float16*)C)[(size_t)(row + r) * N + col] = cvh(v);
        else
          ((float*)C)[(size_t)(row + r) * N + col] = v;
      }
    }
  }
}

// ---------------------------------------------------------------------------
extern "C" void kernel_launch(void* const* d_in, const int* in_sizes, int n_in,
                              void* d_out, int out_size, void* d_ws, size_t ws_size,
                              hipStream_t stream) {
  const float* x  = (const float*)d_in[0];
  const float* a0 = (const float*)d_in[1];
  const float* s0 = (const float*)d_in[2];
  const float* b0 = (const float*)d_in[3];
  const float* a1 = (const float*)d_in[4];
  const float* s1 = (const float*)d_in[5];
  const float* b1 = (const float*)d_in[6];
  const float* W  = (const float*)d_in[7];
  const float* bb = (const float*)d_in[8];

  const int Bn = 16384, D = 512, KK = 3584, DOUT = 256;
  const size_t szF  = (size_t)Bn * KK * 2;  // 117,440,512
  const size_t szFb = (size_t)Bn * KK;      //  58,720,256 (byte lo)
  const size_t szH  = (size_t)Bn * D * 4;   //  33,554,432
  const size_t szW  = (size_t)D * KK * 2;   //   3,670,016
  const size_t szP  = (size_t)DOUT * D * 2; //     262,144
  const size_t needA = szF + szFb + szH + 3 * szW + szP + 4096;  // ~221.0 MB

  if (ws_size >= needA) {
    // ---- pipeline A: pre-featurized hi/byte-lo layer-1 ----
    char* p = (char*)d_ws;
    _Float16*      Fhi  = (_Float16*)p; p += szF;       // reused as layer-2 Afeat
    unsigned char* FloB = (unsigned char*)p; p += szFb;
    float*    h     = (float*)p;
    _Float16* ghalf = (_Float16*)p; p += szH;
    _Float16* Wh0   = (_Float16*)p; p += szW;
    _Float16* Wl0   = (_Float16*)p; p += szW;
    _Float16* Wh1   = (_Float16*)p; p += szW;
    _Float16* WpT   = (_Float16*)p; p += szP;
    float*    biasv = (float*)p;

    prep_weights<true ><<<dim3(512), dim3(512), 0, stream>>>(a0, s0, b0, Wh0, Wl0, biasv);
    prep_weights<false><<<dim3(512), dim3(512), 0, stream>>>(a1, s1, b1, Wh1, nullptr, biasv + 512);
    cvt_half_k<<<dim3(512), dim3(256), 0, stream>>>(W, WpT, DOUT * D);

    featurize_hilo<<<dim3(Bn * 64 / 256), dim3(256), 0, stream>>>(x, Fhi, FloB);
    gemm_l1_pre<<<dim3(512), dim3(256), 0, stream>>>(Fhi, FloB, Wh0, Wl0, biasv, h);

    featurize8<<<dim3(Bn * 64 / 256), dim3(256), 0, stream>>>(h, Fhi);
    gemm_tn<true><<<dim3(512), dim3(256), 0, stream>>>(Fhi, Wh1, biasv + 512, ghalf,
                                                       Bn, D, KK, 2, 512, WDESCALE);

    gemm_tn<false><<<dim3(256), dim3(256), 0, stream>>>(ghalf, WpT, bb, (float*)d_out,
                                                        Bn, DOUT, D, 1, 256, PDESCALE);
  } else {
    // ---- pipeline B (proven fallback): fused featurize layer-1 ----
    char* p = (char*)d_ws;
    _Float16* Afeat = (_Float16*)p;
    _Float16* Wh0   = (_Float16*)p;
    _Float16* Wl0   = (_Float16*)(p + szW);
    p += szF;
    float*    h     = (float*)p;
    _Float16* ghalf = (_Float16*)p;
    p += szH;
    _Float16* Wh1   = (_Float16*)p; p += szW;
    _Float16* WpT   = (_Float16*)p; p += szP;
    float*    biasv = (float*)p;

    prep_weights<true ><<<dim3(512), dim3(512), 0, stream>>>(a0, s0, b0, Wh0, Wl0, biasv);
    prep_weights<false><<<dim3(512), dim3(512), 0, stream>>>(a1, s1, b1, Wh1, nullptr, biasv + 512);
    cvt_half_k<<<dim3(512), dim3(256), 0, stream>>>(W, WpT, DOUT * D);

    gemm_l1_fused<<<dim3(512), dim3(256), 0, stream>>>(x, Wh0, Wl0, biasv, h);

    featurize8<<<dim3(Bn * 64 / 256), dim3(256), 0, stream>>>(h, Afeat);
    gemm_tn<true><<<dim3(512), dim3(256), 0, stream>>>(Afeat, Wh1, biasv + 512, ghalf,
                                                       Bn, D, KK, 2, 512, WDESCALE);

    gemm_tn<false><<<dim3(256), dim3(256), 0, stream>>>(ghalf, WpT, bb, (float*)d_out,
                                                        Bn, DOUT, D, 1, 256, PDESCALE);
  }
}

// Round 7
// 346.708 us; speedup vs baseline: 1.3989x; 1.0037x over previous
//
#include <hip/hip_runtime.h>
#include <string.h>

typedef _Float16 f16x8 __attribute__((ext_vector_type(8)));
typedef float f32x4 __attribute__((ext_vector_type(4)));

#define EXP_CLIP 10.0f
#define FEPS 1e-6f
#define WSCALE 16384.0f      // 2^14 weight prescale (kills fp16-denorm weights)
#define WDESCALE (1.0f/16384.0f)
#define PSCALE 1024.0f       // proj weight prescale
#define PDESCALE (1.0f/1024.0f)

__device__ __forceinline__ _Float16 cvh(float v) {
  v = fminf(fmaxf(v, -60000.f), 60000.f);
  return (_Float16)v;
}

__device__ __forceinline__ void gload_lds16(const void* g, void* l) {
  __builtin_amdgcn_global_load_lds(
      (const __attribute__((address_space(1))) void*)g,
      (__attribute__((address_space(3))) void*)l, 16, 0, 0);
}

// XOR-swizzled LDS offset (half units) for a [*][64]-half tile.
__device__ __forceinline__ int swz(int row, int colh) {
  return row * 64 + (colh ^ ((row & 7) << 3));
}

__device__ __forceinline__ float prim_eval(int kp, float x) {
  switch (kp) {
    case 0: return x;
    case 1: return x * x;
    case 2: return x * x * x;
    case 3: return __expf(fminf(fmaxf(x, -EXP_CLIP), EXP_CLIP));
    case 4: return __logf(fabsf(x) + FEPS);
    case 5: return x / (x * x + FEPS);
    default: return __sinf(x);
  }
}

// e5m2 encode (RNE) of a small residual: fp16 bits -> top byte with rounding.
__device__ __forceinline__ unsigned char enc_e5m2(float lo) {
  _Float16 lh = (_Float16)lo;
  unsigned short u;
  memcpy(&u, &lh, 2);
  unsigned t = (unsigned)u + 0x7Fu + ((u >> 8) & 1u);
  return (unsigned char)(t >> 8);
}

// ---------------------------------------------------------------------------
// Prep: per (layer, j) block, 512 threads over i.
// ---------------------------------------------------------------------------
template <bool EMIT_LO>
__global__ __launch_bounds__(512)
void prep_weights(const float* __restrict__ alphas, const float* __restrict__ scale,
                  const float* __restrict__ bias, _Float16* __restrict__ Wh,
                  _Float16* __restrict__ Wl, float* __restrict__ biasvec) {
  int j = blockIdx.x;
  int i = threadIdx.x;
  size_t base = ((size_t)i * 512 + j) * 8;
  float a[8];
#pragma unroll
  for (int k = 0; k < 8; ++k) a[k] = alphas[base + k];
  float m = a[0];
#pragma unroll
  for (int k = 1; k < 8; ++k) m = fmaxf(m, a[k]);
  float e[8], sum = 0.f;
#pragma unroll
  for (int k = 0; k < 8; ++k) { e[k] = __expf(a[k] - m); sum += e[k]; }
  float inv = 1.f / sum;
  float bp = 0.f;
#pragma unroll
  for (int k = 1; k < 8; ++k) {
    float w = e[k] * inv;
    float ws = fminf(fmaxf(w * scale[base + k] * WSCALE, -60000.f), 60000.f);
    _Float16 wh = (_Float16)ws;
    size_t o = (size_t)j * 3584 + (size_t)(k - 1) * 512 + i;
    Wh[o] = wh;
    if (EMIT_LO) Wl[o] = (_Float16)(ws - (float)wh);
    bp += w * bias[base + k];
  }
  __shared__ float red[512];
  red[i] = bp;
  __syncthreads();
  for (int off = 256; off > 0; off >>= 1) {
    if (i < off) red[i] += red[i + off];
    __syncthreads();
  }
  if (i == 0) biasvec[j] = red[0];
}

// ---------------------------------------------------------------------------
// Pre-featurize x -> Fhi fp16 + FloB e5m2-byte, both [16384][3584].
// ---------------------------------------------------------------------------
__global__ __launch_bounds__(256)
void featurize_hilo(const float* __restrict__ in, _Float16* __restrict__ hi,
                    unsigned char* __restrict__ loB) {
  int t = blockIdx.x * 256 + threadIdx.x;    // 16384*64 threads
  int b = t >> 6, g = (t & 63) * 8;
  const float* xp = in + (size_t)b * 512 + g;
  float4 a = *(const float4*)xp;
  float4 c = *(const float4*)(xp + 4);
  float xv[8] = {a.x, a.y, a.z, a.w, c.x, c.y, c.z, c.w};
  _Float16* oh = hi + (size_t)b * 3584 + g;
  unsigned char* ol = loB + (size_t)b * 3584 + g;
#pragma unroll
  for (int kp = 0; kp < 7; ++kp) {
    f16x8 hv;
    unsigned long long lb = 0;
#pragma unroll
    for (int e = 0; e < 8; ++e) {
      float f = prim_eval(kp, xv[e]);
      _Float16 fh = (_Float16)f;
      hv[e] = fh;
      lb |= (unsigned long long)enc_e5m2(f - (float)fh) << (8 * e);
    }
    *(f16x8*)&oh[kp * 512] = hv;
    *(unsigned long long*)&ol[kp * 512] = lb;
  }
}

// ---------------------------------------------------------------------------
// Featurize (layer-2 input): h [rows][512] fp32 -> out [rows][3584] fp16.
// ---------------------------------------------------------------------------
__global__ __launch_bounds__(256)
void featurize8(const float* __restrict__ in, _Float16* __restrict__ out) {
  int t = blockIdx.x * 256 + threadIdx.x;
  int b = t >> 6, g = (t & 63) * 8;
  const float* xp = in + (size_t)b * 512 + g;
  float4 a = *(const float4*)xp;
  float4 c = *(const float4*)(xp + 4);
  float xv[8] = {a.x, a.y, a.z, a.w, c.x, c.y, c.z, c.w};
  _Float16* o = out + (size_t)b * 3584 + g;
#pragma unroll
  for (int kp = 0; kp < 7; ++kp) {
    f16x8 v;
#pragma unroll
    for (int e = 0; e < 8; ++e) v[e] = cvh(prim_eval(kp, xv[e]));
    *(f16x8*)&o[kp * 512] = v;
  }
}

__global__ __launch_bounds__(256)
void cvt_half_k(const float* __restrict__ in, _Float16* __restrict__ out, int n) {
  int idx = blockIdx.x * 256 + threadIdx.x;
  if (idx < n) out[idx] = (_Float16)(in[idx] * PSCALE);
}

// ---------------------------------------------------------------------------
// Layer-1 GEMM (pipeline A): 3-term split GEMM on pre-featurized A.
// A-hi fp16 (swizzled), A-lo e5m2 bytes (16B-pair XOR-swizzled: pair' =
// pair ^ ((row>>1)&3), applied via pre-swizzled global source + same XOR on
// the b64 read -> 4 dwords/bank = conflict-free minimum), B-hi/B-lo fp16
// (swizzled). 128x128, BK=64, 4 waves, 56 KB LDS (2 blk/CU).
// ---------------------------------------------------------------------------
__global__ __launch_bounds__(256)
void gemm_l1_pre(const _Float16* __restrict__ Fhi, const unsigned char* __restrict__ FloB,
                 const _Float16* __restrict__ Wh, const _Float16* __restrict__ Wl,
                 const float* __restrict__ bias, float* __restrict__ H) {
  __shared__ __align__(16) _Float16 AhS[128 * 64];       // 16 KB
  __shared__ __align__(16) unsigned char AlB[128 * 64];  //  8 KB
  __shared__ __align__(16) _Float16 BhS[128 * 64];       // 16 KB
  __shared__ __align__(16) _Float16 BlS[128 * 64];       // 16 KB
  const int K = 3584;
  int lin = blockIdx.x;                 // 512 blocks
  int wg = (lin & 7) * 64 + (lin >> 3); // XCD-contiguous remap
  int bn = wg & 3, bm = wg >> 2;        // bn fast: 4 col-blocks share A panel in XCD-L2
  int row0 = bm * 128, col0 = bn * 128;
  int tid = threadIdx.x, lane = tid & 63, wave = tid >> 6;
  int wm = wave >> 1, wn = wave & 1;
  int l16 = lane & 15, lh = lane >> 4;
  int sr = lane >> 3, sc = ((lane & 7) * 8) ^ (sr << 3);  // pre-swizzled src col (halves)
  int br = lane >> 2;                                     // byte-tile staging row 0..15
  int bp_ = lane & 3;                                     // 16B pair index 0..3
  int bcs = (bp_ ^ ((br >> 1) & 3)) * 16;                 // pre-swizzled src col (bytes)

  f32x4 acc[4][4];
#pragma unroll
  for (int m = 0; m < 4; ++m)
#pragma unroll
    for (int n = 0; n < 4; ++n) acc[m][n] = (f32x4){0.f, 0.f, 0.f, 0.f};

  for (int kk0 = 0; kk0 < K; kk0 += 64) {
    const _Float16* Agh = Fhi + (size_t)row0 * K + kk0;
    const unsigned char* Agl = FloB + (size_t)row0 * K + kk0;
    const _Float16* Bgh = Wh + (size_t)col0 * K + kk0;
    const _Float16* Bgl = Wl + (size_t)col0 * K + kk0;
#pragma unroll
    for (int it = 0; it < 4; ++it) {
      int chunk = it * 4 + wave;          // 0..15
      int r = chunk * 8 + sr;
      size_t go = (size_t)r * K + sc;
      gload_lds16(Agh + go, AhS + chunk * 512);
      gload_lds16(Bgh + go, BhS + chunk * 512);
      gload_lds16(Bgl + go, BlS + chunk * 512);
    }
#pragma unroll
    for (int it = 0; it < 2; ++it) {
      int chunk = it * 4 + wave;          // 0..7, 16 rows each
      int r = chunk * 16 + br;
      gload_lds16(Agl + (size_t)r * K + bcs, AlB + chunk * 1024);
    }
    __syncthreads();
#pragma unroll
    for (int kc = 0; kc < 2; ++kc) {
      f16x8 ah[4], al[4];
#pragma unroll
      for (int m = 0; m < 4; ++m) {
        int row = wm * 64 + m * 16 + l16;
        ah[m] = *(const f16x8*)&AhS[swz(row, kc * 32 + lh * 8)];
        // A-lo: 8 e5m2 bytes (pair-swizzled) -> 8 fp16 (byte<<8)
        int cbyte = (kc * 32 + lh * 8) ^ (((row >> 1) & 3) << 4);
        uint2 d = *(const uint2*)&AlB[row * 64 + cbyte];
        union { unsigned u[4]; f16x8 v; } ex;
        ex.u[0] = ((d.x << 8) & 0xFF00u) | ((d.x << 16) & 0xFF000000u);
        ex.u[1] = ((d.x >> 8) & 0xFF00u) | (d.x & 0xFF000000u);
        ex.u[2] = ((d.y << 8) & 0xFF00u) | ((d.y << 16) & 0xFF000000u);
        ex.u[3] = ((d.y >> 8) & 0xFF00u) | (d.y & 0xFF000000u);
        al[m] = ex.v;
      }
#pragma unroll
      for (int n = 0; n < 4; ++n) {
        int ob = swz(wn * 64 + n * 16 + l16, kc * 32 + lh * 8);
        f16x8 bh = *(const f16x8*)&BhS[ob];
        f16x8 bl = *(const f16x8*)&BlS[ob];
#pragma unroll
        for (int m = 0; m < 4; ++m) {
          acc[m][n] = __builtin_amdgcn_mfma_f32_16x16x32_f16(ah[m], bh, acc[m][n], 0, 0, 0);
          acc[m][n] = __builtin_amdgcn_mfma_f32_16x16x32_f16(al[m], bh, acc[m][n], 0, 0, 0);
          acc[m][n] = __builtin_amdgcn_mfma_f32_16x16x32_f16(ah[m], bl, acc[m][n], 0, 0, 0);
        }
      }
    }
    __syncthreads();
  }

#pragma unroll
  for (int m = 0; m < 4; ++m) {
    int row = row0 + wm * 64 + m * 16 + lh * 4;
#pragma unroll
    for (int n = 0; n < 4; ++n) {
      int col = col0 + wn * 64 + n * 16 + l16;
      float bv = bias[col];
#pragma unroll
      for (int r = 0; r < 4; ++r)
        H[(size_t)(row + r) * 512 + col] = acc[m][n][r] * WDESCALE + bv;
    }
  }
}

// ---------------------------------------------------------------------------
// Layer-1 fused GEMM (pipeline B fallback, proven): featurize in-loop.
// ---------------------------------------------------------------------------
__global__ __launch_bounds__(256, 2)
void gemm_l1_fused(const float* __restrict__ X, const _Float16* __restrict__ Wh,
                   const _Float16* __restrict__ Wl, const float* __restrict__ bias,
                   float* __restrict__ H) {
  __shared__ __align__(16) _Float16 AhS[128 * 64];
  __shared__ __align__(16) _Float16 AlS[128 * 64];
  __shared__ __align__(16) _Float16 BhS[128 * 64];
  __shared__ __align__(16) _Float16 BlS[128 * 64];
  const int K = 3584;
  int lin = blockIdx.x;
  int wg = (lin & 7) * 64 + (lin >> 3);
  int bn = wg & 3, bm = wg >> 2;
  int row0 = bm * 128, col0 = bn * 128;
  int tid = threadIdx.x, lane = tid & 63, wave = tid >> 6;
  int wm = wave >> 1, wn = wave & 1;
  int l16 = lane & 15, lh = lane >> 4;
  int sr = lane >> 3, sc = ((lane & 7) * 8) ^ (sr << 3);
  int ar = tid >> 3, ac = (tid & 7) * 8;

  f32x4 acc[4][4];
#pragma unroll
  for (int m = 0; m < 4; ++m)
#pragma unroll
    for (int n = 0; n < 4; ++n) acc[m][n] = (f32x4){0.f, 0.f, 0.f, 0.f};

#pragma unroll 1
  for (int kk0 = 0; kk0 < K; kk0 += 64) {
    int kp = kk0 >> 9, i0 = kk0 & 511;
    const _Float16* Bgh = Wh + (size_t)col0 * K + kk0;
    const _Float16* Bgl = Wl + (size_t)col0 * K + kk0;
#pragma unroll
    for (int it = 0; it < 4; ++it) {
      int chunk = it * 4 + wave;
      int r = chunk * 8 + sr;
      gload_lds16(Bgh + (size_t)r * K + sc, BhS + chunk * 512);
      gload_lds16(Bgl + (size_t)r * K + sc, BlS + chunk * 512);
    }
#pragma unroll
    for (int it = 0; it < 4; ++it) {
      int r = it * 32 + ar;
      const float* xp = X + (size_t)(row0 + r) * 512 + i0 + ac;
      float4 x01 = *(const float4*)xp;
      float4 x23 = *(const float4*)(xp + 4);
      float xv[8] = {x01.x, x01.y, x01.z, x01.w, x23.x, x23.y, x23.z, x23.w};
      f16x8 hv, lv;
#pragma unroll
      for (int e = 0; e < 8; ++e) {
        float f = prim_eval(kp, xv[e]);
        _Float16 fh = (_Float16)f;
        hv[e] = fh;
        lv[e] = (_Float16)(f - (float)fh);
      }
      int wo = swz(r, ac);
      *(f16x8*)&AhS[wo] = hv;
      *(f16x8*)&AlS[wo] = lv;
    }
    __syncthreads();
#pragma unroll
    for (int kc = 0; kc < 2; ++kc) {
      f16x8 ah[4], al[4];
#pragma unroll
      for (int m = 0; m < 4; ++m) {
        int off = swz(wm * 64 + m * 16 + l16, kc * 32 + lh * 8);
        ah[m] = *(const f16x8*)&AhS[off];
        al[m] = *(const f16x8*)&AlS[off];
      }
#pragma unroll
      for (int n = 0; n < 4; ++n) {
        int ob = swz(wn * 64 + n * 16 + l16, kc * 32 + lh * 8);
        f16x8 bh = *(const f16x8*)&BhS[ob];
        f16x8 bl = *(const f16x8*)&BlS[ob];
#pragma unroll
        for (int m = 0; m < 4; ++m) {
          acc[m][n] = __builtin_amdgcn_mfma_f32_16x16x32_f16(ah[m], bh, acc[m][n], 0, 0, 0);
          acc[m][n] = __builtin_amdgcn_mfma_f32_16x16x32_f16(al[m], bh, acc[m][n], 0, 0, 0);
          acc[m][n] = __builtin_amdgcn_mfma_f32_16x16x32_f16(ah[m], bl, acc[m][n], 0, 0, 0);
        }
      }
    }
    __syncthreads();
  }

#pragma unroll
  for (int m = 0; m < 4; ++m) {
    int row = row0 + wm * 64 + m * 16 + lh * 4;
#pragma unroll
    for (int n = 0; n < 4; ++n) {
      int col = col0 + wn * 64 + n * 16 + l16;
      float bv = bias[col];
#pragma unroll
      for (int r = 0; r < 4; ++r)
        H[(size_t)(row + r) * 512 + col] = acc[m][n][r] * WDESCALE + bv;
    }
  }
}

// ---------------------------------------------------------------------------
// Plain fp16 GEMM: C[M][N] = A[M][K] * BT[N][K]^T * outscale + bias[N]
// ---------------------------------------------------------------------------
template <bool OUT_HALF>
__global__ __launch_bounds__(256)
void gemm_tn(const _Float16* __restrict__ A, const _Float16* __restrict__ BT,
             const float* __restrict__ bias, void* __restrict__ C,
             int M, int N, int K, int nbn_log2, int nwg, float outscale) {
  __shared__ __align__(16) _Float16 Ash[128 * 64];
  __shared__ __align__(16) _Float16 Bsh[128 * 64];
  int lin = blockIdx.x;
  int q = nwg >> 3;
  int wg = (lin & 7) * q + (lin >> 3);
  int bn = wg & ((1 << nbn_log2) - 1);
  int bm = wg >> nbn_log2;
  int row0 = bm * 128, col0 = bn * 128;
  int tid = threadIdx.x, lane = tid & 63, wave = tid >> 6;
  int wm = wave >> 1, wn = wave & 1;
  int l16 = lane & 15, lh = lane >> 4;
  int sr = lane >> 3;
  int sc = ((lane & 7) * 8) ^ (sr << 3);

  f32x4 acc[4][4];
#pragma unroll
  for (int m = 0; m < 4; ++m)
#pragma unroll
    for (int n = 0; n < 4; ++n) acc[m][n] = (f32x4){0.f, 0.f, 0.f, 0.f};

  for (int kk0 = 0; kk0 < K; kk0 += 64) {
    const _Float16* Ag = A + (size_t)row0 * K + kk0;
    const _Float16* Bg = BT + (size_t)col0 * K + kk0;
#pragma unroll
    for (int it = 0; it < 4; ++it) {
      int chunk = it * 4 + wave;
      int r = chunk * 8 + sr;
      gload_lds16(Ag + (size_t)r * K + sc, Ash + chunk * 512);
      gload_lds16(Bg + (size_t)r * K + sc, Bsh + chunk * 512);
    }
    __syncthreads();
#pragma unroll
    for (int kc = 0; kc < 2; ++kc) {
      f16x8 af[4], bf[4];
#pragma unroll
      for (int m = 0; m < 4; ++m)
        af[m] = *(const f16x8*)&Ash[swz(wm * 64 + m * 16 + l16, kc * 32 + lh * 8)];
#pragma unroll
      for (int n = 0; n < 4; ++n)
        bf[n] = *(const f16x8*)&Bsh[swz(wn * 64 + n * 16 + l16, kc * 32 + lh * 8)];
#pragma unroll
      for (int m = 0; m < 4; ++m)
#pragma unroll
        for (int n = 0; n < 4; ++n)
          acc[m][n] = __builtin_amdgcn_mfma_f32_16x16x32_f16(af[m], bf[n], acc[m][n], 0, 0, 0);
    }
    __syncthreads();
  }

#pragma unroll
  for (int m = 0; m < 4; ++m) {
    int row = row0 + wm * 64 + m * 16 + lh * 4;
#pragma unroll
    for (int n = 0; n < 4; ++n) {
      int col = col0 + wn * 64 + n * 16 + l16;
      float bv = bias[col];
#pragma unroll
      for (int r = 0; r < 4; ++r) {
        float v = acc[m][n][r] * outscale + bv;
        if (OUT_HALF)
          ((_Float16*)C)[(size_t)(row + r) * N + col] = cvh(v);
        else
          ((float*)C)[(size_t)(row + r) * N + col] = v;
      }
    }
  }
}

// ---------------------------------------------------------------------------
extern "C" void kernel_launch(void* const* d_in, const int* in_sizes, int n_in,
                              void* d_out, int out_size, void* d_ws, size_t ws_size,
                              hipStream_t stream) {
  const float* x  = (const float*)d_in[0];
  const float* a0 = (const float*)d_in[1];
  const float* s0 = (const float*)d_in[2];
  const float* b0 = (const float*)d_in[3];
  const float* a1 = (const float*)d_in[4];
  const float* s1 = (const float*)d_in[5];
  const float* b1 = (const float*)d_in[6];
  const float* W  = (const float*)d_in[7];
  const float* bb = (const float*)d_in[8];

  const int Bn = 16384, D = 512, KK = 3584, DOUT = 256;
  const size_t szF  = (size_t)Bn * KK * 2;  // 117,440,512
  const size_t szFb = (size_t)Bn * KK;      //  58,720,256 (byte lo)
  const size_t szH  = (size_t)Bn * D * 4;   //  33,554,432
  const size_t szW  = (size_t)D * KK * 2;   //   3,670,016
  const size_t szP  = (size_t)DOUT * D * 2; //     262,144
  const size_t needA = szF + szFb + szH + 3 * szW + szP + 4096;  // ~221.0 MB

  if (ws_size >= needA) {
    // ---- pipeline A: pre-featurized hi/byte-lo layer-1 ----
    char* p = (char*)d_ws;
    _Float16*      Fhi  = (_Float16*)p; p += szF;       // reused as layer-2 Afeat
    unsigned char* FloB = (unsigned char*)p; p += szFb;
    float*    h     = (float*)p;
    _Float16* ghalf = (_Float16*)p; p += szH;
    _Float16* Wh0   = (_Float16*)p; p += szW;
    _Float16* Wl0   = (_Float16*)p; p += szW;
    _Float16* Wh1   = (_Float16*)p; p += szW;
    _Float16* WpT   = (_Float16*)p; p += szP;
    float*    biasv = (float*)p;

    prep_weights<true ><<<dim3(512), dim3(512), 0, stream>>>(a0, s0, b0, Wh0, Wl0, biasv);
    prep_weights<false><<<dim3(512), dim3(512), 0, stream>>>(a1, s1, b1, Wh1, nullptr, biasv + 512);
    cvt_half_k<<<dim3(512), dim3(256), 0, stream>>>(W, WpT, DOUT * D);

    featurize_hilo<<<dim3(Bn * 64 / 256), dim3(256), 0, stream>>>(x, Fhi, FloB);
    gemm_l1_pre<<<dim3(512), dim3(256), 0, stream>>>(Fhi, FloB, Wh0, Wl0, biasv, h);

    featurize8<<<dim3(Bn * 64 / 256), dim3(256), 0, stream>>>(h, Fhi);
    gemm_tn<true><<<dim3(512), dim3(256), 0, stream>>>(Fhi, Wh1, biasv + 512, ghalf,
                                                       Bn, D, KK, 2, 512, WDESCALE);

    gemm_tn<false><<<dim3(256), dim3(256), 0, stream>>>(ghalf, WpT, bb, (float*)d_out,
                                                        Bn, DOUT, D, 1, 256, PDESCALE);
  } else {
    // ---- pipeline B (proven fallback): fused featurize layer-1 ----
    char* p = (char*)d_ws;
    _Float16* Afeat = (_Float16*)p;
    _Float16* Wh0   = (_Float16*)p;
    _Float16* Wl0   = (_Float16*)(p + szW);
    p += szF;
    float*    h     = (float*)p;
    _Float16* ghalf = (_Float16*)p;
    p += szH;
    _Float16* Wh1   = (_Float16*)p; p += szW;
    _Float16* WpT   = (_Float16*)p; p += szP;
    float*    biasv = (float*)p;

    prep_weights<true ><<<dim3(512), dim3(512), 0, stream>>>(a0, s0, b0, Wh0, Wl0, biasv);
    prep_weights<false><<<dim3(512), dim3(512), 0, stream>>>(a1, s1, b1, Wh1, nullptr, biasv + 512);
    cvt_half_k<<<dim3(512), dim3(256), 0, stream>>>(W, WpT, DOUT * D);

    gemm_l1_fused<<<dim3(512), dim3(256), 0, stream>>>(x, Wh0, Wl0, biasv, h);

    featurize8<<<dim3(Bn * 64 / 256), dim3(256), 0, stream>>>(h, Afeat);
    gemm_tn<true><<<dim3(512), dim3(256), 0, stream>>>(Afeat, Wh1, biasv + 512, ghalf,
                                                       Bn, D, KK, 2, 512, WDESCALE);

    gemm_tn<false><<<dim3(256), dim3(256), 0, stream>>>(ghalf, WpT, bb, (float*)d_out,
                                                        Bn, DOUT, D, 1, 256, PDESCALE);
  }
}